// Round 10
// baseline (661.178 us; speedup 1.0000x reference)
//
#include <hip/hip_runtime.h>

#define TID threadIdx.x

constexpr int B = 2, C = 256, N = 2048, H = 8, D = 32, BH = 16;
constexpr float EPS = 1e-5f;
constexpr float SCL2 = 0.25505654344454694f; // 32^-0.5 * log2(e)
constexpr size_t SZ = (size_t)BH * N * D;    // 1048576 elements per Q/K/V buffer

typedef _Float16 h8 __attribute__((ext_vector_type(8)));
typedef _Float16 h4 __attribute__((ext_vector_type(4)));
typedef float f32x4 __attribute__((ext_vector_type(4)));

// ---------------- kernel 1: batchnorm stats (mean, rstd per channel) ----------------
__global__ __launch_bounds__(256) void k_bnstats(const float* __restrict__ x,
                                                 float* __restrict__ stats) {
  int c = blockIdx.x;
  float s = 0.f, ss = 0.f;
  const float4* x4 = (const float4*)x;
  for (int k = 0; k < B; ++k) {
    const float4* p = x4 + (size_t)(k * C + c) * (N / 4);
    for (int i = TID; i < N / 4; i += 256) {
      float4 v = p[i];
      s += v.x + v.y + v.z + v.w;
      ss += v.x * v.x + v.y * v.y + v.z * v.z + v.w * v.w;
    }
  }
#pragma unroll
  for (int off = 32; off; off >>= 1) {
    s += __shfl_down(s, off);
    ss += __shfl_down(ss, off);
  }
  __shared__ float red[8];
  int w = TID >> 6;
  if ((TID & 63) == 0) { red[w] = s; red[4 + w] = ss; }
  __syncthreads();
  if (TID == 0) {
    float S = red[0] + red[1] + red[2] + red[3];
    float SS = red[4] + red[5] + red[6] + red[7];
    float mean = S * (1.f / (B * N));
    float var = SS * (1.f / (B * N)) - mean * mean;
    stats[c] = mean;
    stats[C + c] = rsqrtf(var + EPS);
  }
}

// ---------------- kernel 2: fused BN-apply + grouped conv projections (fp16 out) --------
// DIAGNOSTIC: runtime `reps` repeats the idempotent body (same output).
__global__ __launch_bounds__(256) void k_proj(const float* __restrict__ x,
    const float* __restrict__ gamma, const float* __restrict__ beta,
    const float* __restrict__ wk, const float* __restrict__ wq,
    const float* __restrict__ wv, const float* __restrict__ stats,
    _Float16* __restrict__ qa, _Float16* __restrict__ ka, _Float16* __restrict__ va,
    int reps) {
  int proj = blockIdx.x >> 8;
  int rem = blockIdx.x & 255;
  int b = rem >> 7;
  int n0 = (rem & 127) * 16;
  const float* w = proj == 0 ? wk : (proj == 1 ? wq : wv);
  _Float16* out = proj == 0 ? qa : (proj == 1 ? ka : va);

  __shared__ float w_s[256 * 33];  // row (d + 32h) holds w[8d+h][*]
  __shared__ float xs[256 * 20];   // row (g + 8c) holds xn channel g*32+c

  for (int rep = 0; rep < reps; ++rep) {
    __syncthreads();
#pragma unroll
    for (int p = 0; p < 32; ++p) {
      int ch = p * 8 + (TID >> 5);
      int cc = TID & 31;
      float wval = w[ch * 32 + cc];
      int row = (ch >> 3) + ((ch & 7) << 5);  // d + 32h
      w_s[row * 33 + cc] = wval;
    }
#pragma unroll
    for (int p = 0; p < 16; ++p) {
      int cc = p * 16 + (TID >> 4);
      int nl = TID & 15;
      float v = x[(size_t)(b * C + cc) * N + n0 + nl];
      float a = stats[C + cc] * gamma[cc];
      float xn = (v - stats[cc]) * a + beta[cc];
      int row = (cc >> 5) + ((cc & 31) << 3);  // g + 8c
      xs[row * 20 + nl] = xn;
    }
    __syncthreads();

    int d = TID & 31;
    int t2 = TID >> 5;  // n = n0 + t2*2 + {0,1}
#pragma unroll
    for (int h = 0; h < 8; ++h) {
      int g = (d * 8 + h) >> 5;
      const float* wrow = &w_s[(d + h * 32) * 33];
      float2 acc = {0.f, 0.f};
#pragma unroll
      for (int c = 0; c < 32; ++c) {
        float wv2 = wrow[c];
        float2 xv = *(const float2*)&xs[(g + c * 8) * 20 + t2 * 2];
        acc.x += wv2 * xv.x;
        acc.y += wv2 * xv.y;
      }
      int n = n0 + t2 * 2;
      size_t bh = (size_t)(b * 8 + h);
      size_t o = (bh * N + n) * D + d;
      out[o] = (_Float16)acc.x;
      out[o + D] = (_Float16)acc.y;
    }
  }
}

// ---------------- kernel 3: MFMA fp16 flash attention (JS=2, exp2 domain) ----------------
// DIAGNOSTIC: runtime `reps` recomputes the whole flash loop (same output).
__global__ __launch_bounds__(256, 4) void k_attn(
    const _Float16* __restrict__ qa, const _Float16* __restrict__ ka,
    const _Float16* __restrict__ va, float* __restrict__ op,
    float* __restrict__ mp, float* __restrict__ lp, int reps) {
  int bid = blockIdx.x;
  int r = bid & 7;          // XCD id (round-robin dispatch)
  int q = bid >> 3;         // 0..127
  int js = q >> 6;
  int bh = r * 2 + ((q >> 5) & 1);
  int rb = q & 31;
  constexpr int ntiles = 16;  // 1024 j's per js half

  int w = TID >> 6;
  int lane = TID & 63;
  int il = lane & 15;
  int g = lane >> 4;

  __shared__ char Kc[4096];      // K tile [64 j][32 d] fp16, rows 64B, swz ^((j&3)<<4)
  __shared__ char Vc[4096];      // V^T tile [32 d][64 j] fp16, rows 128B, swz f(d)
  __shared__ char Pc[4 * 2048];  // per-wave P^T [16 i][64 j] fp16, swz ^((i&7)<<4)
  char* Pw = Pc + w * 2048;

  int n_q = rb * 64 + w * 16 + il;
  h8 qf = *(const h8*)(qa + ((size_t)bh * N + n_q) * D + g * 8);

  int kj = TID >> 2, kc = TID & 3;
  const _Float16* kbase = ka + ((size_t)bh * N + (size_t)js * 1024 + kj) * D + kc * 8;
  const _Float16* vbase = va + ((size_t)bh * N + (size_t)js * 1024 + kj) * D + kc * 8;
  int kdst = (kj * 64 + kc * 16) ^ ((kj & 3) << 4);

  f32x4 accO[2];
  float m, l;

  for (int rep = 0; rep < reps; ++rep) {
#pragma unroll
    for (int dh = 0; dh < 2; ++dh) accO[dh] = (f32x4){0.f, 0.f, 0.f, 0.f};
    m = -3.0e38f;
    l = 0.f;
    h8 kreg = *(const h8*)kbase;
    h8 vreg = *(const h8*)vbase;

    for (int t = 0; t < ntiles; ++t) {
      __syncthreads();
      *(h8*)(Kc + kdst) = kreg;
#pragma unroll
      for (int e = 0; e < 8; ++e) {  // V transpose-scatter
        int d = kc * 8 + e;
        int addr = (d * 128 + kj * 2) ^ ((d & 7) << 4) ^ (((d >> 3) & 3) << 5);
        *(_Float16*)(Vc + addr) = vreg[e];
      }
      if (t + 1 < ntiles) {
        kreg = *(const h8*)(kbase + (size_t)(t + 1) * 64 * D);
        vreg = *(const h8*)(vbase + (size_t)(t + 1) * 64 * D);
      }
      __syncthreads();

      // ---- QK^T -> scores in log2 domain ----
      float pv[4][4];
      float tmax = -3.0e38f;
#pragma unroll
      for (int jt = 0; jt < 4; ++jt) {
        int krow = jt * 16 + il;
        h8 kf = *(const h8*)(Kc + ((krow * 64 + g * 16) ^ ((krow & 3) << 4)));
        f32x4 accS = (f32x4){0.f, 0.f, 0.f, 0.f};
        accS = __builtin_amdgcn_mfma_f32_16x16x32_f16(kf, qf, accS, 0, 0, 0);
#pragma unroll
        for (int e = 0; e < 4; ++e) {
          float xv = accS[e] * SCL2;
          pv[jt][e] = xv;
          tmax = fmaxf(tmax, xv);
        }
      }
      tmax = fmaxf(tmax, __shfl_xor(tmax, 16));
      tmax = fmaxf(tmax, __shfl_xor(tmax, 32));
      float mn = fmaxf(m, tmax);
      float corr = exp2f(m - mn);
      float ls = 0.f;
#pragma unroll
      for (int jt = 0; jt < 4; ++jt)
#pragma unroll
        for (int e = 0; e < 4; ++e) {
          float pe = exp2f(pv[jt][e] - mn);
          pv[jt][e] = pe;
          ls += pe;
        }
      ls += __shfl_xor(ls, 16);
      ls += __shfl_xor(ls, 32);
      l = l * corr + ls;
      m = mn;
#pragma unroll
      for (int dh = 0; dh < 2; ++dh)
#pragma unroll
        for (int e = 0; e < 4; ++e) accO[dh][e] *= corr;

      // ---- P -> wave-private LDS ----
#pragma unroll
      for (int jt = 0; jt < 4; ++jt) {
        h4 ph = {(_Float16)pv[jt][0], (_Float16)pv[jt][1],
                 (_Float16)pv[jt][2], (_Float16)pv[jt][3]};
        *(h4*)(Pw + ((il * 128 + jt * 32 + g * 8) ^ ((il & 7) << 4))) = ph;
      }

      // ---- PV ----
#pragma unroll
      for (int jb = 0; jb < 2; ++jb) {
        h8 pf = *(const h8*)(Pw + ((il * 128 + jb * 64 + g * 16) ^ ((il & 7) << 4)));
#pragma unroll
        for (int dh = 0; dh < 2; ++dh) {
          int vrow = dh * 16 + il;
          int vaddr = (vrow * 128 + jb * 64 + g * 16) ^ ((vrow & 7) << 4) ^
                      (((vrow >> 3) & 3) << 5);
          h8 vf = *(const h8*)(Vc + vaddr);
          accO[dh] = __builtin_amdgcn_mfma_f32_16x16x32_f16(vf, pf, accO[dh], 0, 0, 0);
        }
      }
    }
  }

  // epilogue
  int b = bh >> 3, h = bh & 7;
#pragma unroll
  for (int dh = 0; dh < 2; ++dh)
#pragma unroll
    for (int e = 0; e < 4; ++e) {
      int d = dh * 16 + g * 4 + e;
      op[((size_t)((js * 2 + b) * C) + h * 32 + d) * N + n_q] = accO[dh][e];
    }
  if (g == 0) {
    size_t idx = (size_t)(js * BH + bh) * N + n_q;
    mp[idx] = m;
    lp[idx] = l;
  }
}

// ---------------- kernel 4: fused combine + output 1x1 conv ----------------
// DIAGNOSTIC: runtime `reps` repeats the idempotent body (same output).
__global__ __launch_bounds__(256) void k_final(const float* __restrict__ op,
    const float* __restrict__ mp, const float* __restrict__ lp,
    const float* __restrict__ wo, const float* __restrict__ bo,
    float* __restrict__ out, int reps) {
  __shared__ float w_s[256 * 33];   // [c][o_local] transposed, padded
  __shared__ float a_s[256 * 33];   // [c][n_local] combined attention tile
  __shared__ float cwa[8 * 32], cwb[8 * 32];
  int nt = blockIdx.x & 63, oq = (blockIdx.x >> 6) & 7, b = blockIdx.x >> 9;
  int n0 = nt * 32, o0 = oq * 32;

  for (int rep = 0; rep < reps; ++rep) {
    __syncthreads();
    {
      int h = TID >> 5, n_l = TID & 31;
      size_t i0 = (size_t)(b * 8 + h) * N + n0 + n_l;
      size_t i1 = (size_t)(BH + b * 8 + h) * N + n0 + n_l;
      float m0 = mp[i0], m1 = mp[i1];
      float mg = fmaxf(m0, m1);
      float w0 = exp2f(m0 - mg), w1 = exp2f(m1 - mg);
      float inv = 1.f / (w0 * lp[i0] + w1 * lp[i1]);
      cwa[TID] = w0 * inv;
      cwb[TID] = w1 * inv;
    }
#pragma unroll
    for (int p = 0; p < 8; ++p) {
      int idx = p * 256 + TID;
      int o_l = idx >> 6, c4 = idx & 63;
      float4 wv = ((const float4*)wo)[(o0 + o_l) * 64 + c4];
      w_s[(c4 * 4 + 0) * 33 + o_l] = wv.x;
      w_s[(c4 * 4 + 1) * 33 + o_l] = wv.y;
      w_s[(c4 * 4 + 2) * 33 + o_l] = wv.z;
      w_s[(c4 * 4 + 3) * 33 + o_l] = wv.w;
    }
    __syncthreads();
#pragma unroll
    for (int p = 0; p < 8; ++p) {
      int idx = p * 256 + TID;
      int c = idx >> 3, n4 = idx & 7;
      int h = c >> 5;
      size_t base0 = ((size_t)(b * C + c)) * N + n0 + n4 * 4;
      size_t base1 = ((size_t)((2 + b) * C + c)) * N + n0 + n4 * 4;
      float4 v0 = *(const float4*)(op + base0);
      float4 v1 = *(const float4*)(op + base1);
      const float* ca = &cwa[h * 32 + n4 * 4];
      const float* cb = &cwb[h * 32 + n4 * 4];
      a_s[c * 33 + n4 * 4 + 0] = ca[0] * v0.x + cb[0] * v1.x;
      a_s[c * 33 + n4 * 4 + 1] = ca[1] * v0.y + cb[1] * v1.y;
      a_s[c * 33 + n4 * 4 + 2] = ca[2] * v0.z + cb[2] * v1.z;
      a_s[c * 33 + n4 * 4 + 3] = ca[3] * v0.w + cb[3] * v1.w;
    }
    __syncthreads();

    int n_l = TID & 31, og = TID >> 5;
    float acc[4] = {0.f, 0.f, 0.f, 0.f};
    for (int c = 0; c < 256; ++c) {
      float4 w4 = *(const float4*)&w_s[c * 33 + og * 4];
      float av = a_s[c * 33 + n_l];
      acc[0] += w4.x * av;
      acc[1] += w4.y * av;
      acc[2] += w4.z * av;
      acc[3] += w4.w * av;
    }
#pragma unroll
    for (int k = 0; k < 4; ++k) {
      int o = o0 + og * 4 + k;
      out[(size_t)(b * C + o) * N + n0 + n_l] = acc[k] + bo[o];
    }
  }
}

extern "C" void kernel_launch(void* const* d_in, const int* in_sizes, int n_in,
                              void* d_out, int out_size, void* d_ws, size_t ws_size,
                              hipStream_t stream) {
  const float* x = (const float*)d_in[0];
  const float* gamma = (const float*)d_in[1];
  const float* beta = (const float*)d_in[2];
  const float* wk = (const float*)d_in[3];
  const float* wq = (const float*)d_in[4];
  const float* wv = (const float*)d_in[5];
  const float* wo = (const float*)d_in[6];
  const float* bo = (const float*)d_in[7];
  float* out = (float*)d_out;
  float* ws = (float*)d_ws;

  float* stats = ws;
  _Float16* qa = (_Float16*)(ws + 1024);
  _Float16* ka = qa + SZ;
  _Float16* va = ka + SZ;
  float* op = (float*)(va + SZ);          // [js][b][C][N] fp32, 2*SZ floats
  float* mp = op + 2 * SZ;                // [js*BH + bh][N]
  float* lp = mp + 2 * (size_t)BH * N;

  // DIAGNOSTIC: amplify proj/attn/final 8x internally so each appears in the
  // rocprof top-5 with its counters; true per-kernel dur = dispatch_dur / 8.
  k_bnstats<<<256, 256, 0, stream>>>(x, stats);
  k_proj<<<768, 256, 0, stream>>>(x, gamma, beta, wk, wq, wv, stats, qa, ka, va, 8);
  k_attn<<<1024, 256, 0, stream>>>(qa, ka, va, op, mp, lp, 8);
  k_final<<<1024, 256, 0, stream>>>(op, mp, lp, wo, bo, out, 8);
}

// Round 11
// 90.846 us; speedup vs baseline: 7.2780x; 7.2780x over previous
//
#include <hip/hip_runtime.h>

#define TID threadIdx.x

constexpr int B = 2, C = 256, N = 2048, H = 8, D = 32, BH = 16;
constexpr float EPS = 1e-5f;
constexpr float SCL2 = 0.25505654344454694f; // 32^-0.5 * log2(e)
constexpr size_t SZ = (size_t)BH * N * D;    // 1048576 elements per Q/K/V buffer

typedef _Float16 h8 __attribute__((ext_vector_type(8)));
typedef _Float16 h4 __attribute__((ext_vector_type(4)));
typedef float f32x4 __attribute__((ext_vector_type(4)));

// ---------------- kernel 1: batchnorm stats, BN-FOLDED: a = rstd*gamma, bb = beta - mean*a
__global__ __launch_bounds__(256) void k_bnstats(const float* __restrict__ x,
                                                 const float* __restrict__ gamma,
                                                 const float* __restrict__ beta,
                                                 float* __restrict__ stats) {
  int c = blockIdx.x;
  float s = 0.f, ss = 0.f;
  const float4* x4 = (const float4*)x;
  for (int k = 0; k < B; ++k) {
    const float4* p = x4 + (size_t)(k * C + c) * (N / 4);
    for (int i = TID; i < N / 4; i += 256) {
      float4 v = p[i];
      s += v.x + v.y + v.z + v.w;
      ss += v.x * v.x + v.y * v.y + v.z * v.z + v.w * v.w;
    }
  }
#pragma unroll
  for (int off = 32; off; off >>= 1) {
    s += __shfl_down(s, off);
    ss += __shfl_down(ss, off);
  }
  __shared__ float red[8];
  int w = TID >> 6;
  if ((TID & 63) == 0) { red[w] = s; red[4 + w] = ss; }
  __syncthreads();
  if (TID == 0) {
    float S = red[0] + red[1] + red[2] + red[3];
    float SS = red[4] + red[5] + red[6] + red[7];
    float mean = S * (1.f / (B * N));
    float var = SS * (1.f / (B * N)) - mean * mean;
    float a = rsqrtf(var + EPS) * gamma[c];
    stats[c] = a;
    stats[C + c] = beta[c] - mean * a;
  }
}

// ---------------- kernel 2: fused BN-apply + grouped conv projections (fp16 out), v2 ------
// Vectorized staging + folded BN + bank-engineered LDS. Output layout unchanged:
// Qa/Ka/Va fp16 [bh][n][d]; quirk (att (h,d) <- ch d*8+h) and q/k swap applied.
__global__ __launch_bounds__(256) void k_proj(const float* __restrict__ x,
    const float* __restrict__ wk, const float* __restrict__ wq,
    const float* __restrict__ wv, const float* __restrict__ stats,
    _Float16* __restrict__ qa, _Float16* __restrict__ ka, _Float16* __restrict__ va) {
  int proj = blockIdx.x >> 8;
  int rem = blockIdx.x & 255;
  int b = rem >> 7;
  int n0 = (rem & 127) * 16;
  const float* w = proj == 0 ? wk : (proj == 1 ? wq : wv);
  _Float16* out = proj == 0 ? qa : (proj == 1 ? ka : va);

  __shared__ float w_s[256 * 33];  // row (d+32h) = w[8d+h][*]; col' = (c + 5*(row>>5)) & 31
  __shared__ float xs[256 * 18];   // row (g+8c); col' = col ^ ((((row)>>4)&3)<<2)
  __shared__ float sab[512];       // a[c], bb[c]

  // phase 0: BN consts + weight tile (float4 loads, rotated cols)
  sab[TID] = stats[TID];
  sab[256 + TID] = stats[256 + TID];
#pragma unroll
  for (int p = 0; p < 8; ++p) {
    int ch = p * 32 + (TID >> 3);
    int c4 = (TID & 7) * 4;
    float4 wv4 = *(const float4*)(w + ch * 32 + c4);
    int row = (ch >> 3) + ((ch & 7) << 5);  // d + 32h
    int rot = 5 * (row >> 5);
    float* wr = &w_s[row * 33];
    wr[(c4 + 0 + rot) & 31] = wv4.x;
    wr[(c4 + 1 + rot) & 31] = wv4.y;
    wr[(c4 + 2 + rot) & 31] = wv4.z;
    wr[(c4 + 3 + rot) & 31] = wv4.w;
  }
  __syncthreads();
  // phase 1: x tile with BN applied (float4 loads, float2 swizzled LDS writes)
#pragma unroll
  for (int p = 0; p < 4; ++p) {
    int c = p * 64 + (TID >> 2);
    int n4 = (TID & 3) * 4;
    float4 v = *(const float4*)(x + (size_t)(b * C + c) * N + n0 + n4);
    float a = sab[c], bb = sab[256 + c];
    int row = (c >> 5) + ((c & 31) << 3);  // g + 8c
    int swz = ((row >> 4) & 3) << 2;
    float2 lo = {v.x * a + bb, v.y * a + bb};
    float2 hi = {v.z * a + bb, v.w * a + bb};
    *(float2*)&xs[row * 18 + (n4 ^ swz)] = lo;
    *(float2*)&xs[row * 18 + ((n4 + 2) ^ swz)] = hi;
  }
  __syncthreads();

  // compute: d = TID&31, t2 = TID>>5 -> n = n0 + t2*2 + {0,1}
  int d = TID & 31, t2 = TID >> 5;
#pragma unroll
  for (int h = 0; h < 8; ++h) {
    int g = (d * 8 + h) >> 5;
    const float* wrow = &w_s[(d + h * 32) * 33];
    int rot = 5 * h;
    float2 acc = {0.f, 0.f};
#pragma unroll
    for (int c = 0; c < 32; ++c) {
      float wv2 = wrow[(c + rot) & 31];
      int row = g + c * 8;
      int swz = ((row >> 4) & 3) << 2;
      float2 xv = *(const float2*)&xs[row * 18 + ((t2 * 2) ^ swz)];
      acc.x += wv2 * xv.x;
      acc.y += wv2 * xv.y;
    }
    int n = n0 + t2 * 2;
    size_t bh = (size_t)(b * 8 + h);
    size_t o = (bh * N + n) * D + d;
    out[o] = (_Float16)acc.x;
    out[o + D] = (_Float16)acc.y;
  }
}

// ---------------- kernel 3: MFMA fp16 flash attention (JS=2, exp2 domain) ----------------
__global__ __launch_bounds__(256, 4) void k_attn(
    const _Float16* __restrict__ qa, const _Float16* __restrict__ ka,
    const _Float16* __restrict__ va, float* __restrict__ op,
    float* __restrict__ mp, float* __restrict__ lp) {
  int bid = blockIdx.x;
  int r = bid & 7;          // XCD id (round-robin dispatch)
  int q = bid >> 3;         // 0..127
  int js = q >> 6;
  int bh = r * 2 + ((q >> 5) & 1);
  int rb = q & 31;
  constexpr int ntiles = 16;  // 1024 j's per js half

  int w = TID >> 6;
  int lane = TID & 63;
  int il = lane & 15;
  int g = lane >> 4;

  __shared__ char Kc[4096];      // K tile [64 j][32 d] fp16, rows 64B, swz ^((j&3)<<4)
  __shared__ char Vc[4096];      // V^T tile [32 d][64 j] fp16, rows 128B, swz f(d)
  __shared__ char Pc[4 * 2048];  // per-wave P^T [16 i][64 j] fp16, swz ^((i&7)<<4)
  char* Pw = Pc + w * 2048;

  int n_q = rb * 64 + w * 16 + il;
  h8 qf = *(const h8*)(qa + ((size_t)bh * N + n_q) * D + g * 8);

  f32x4 accO[2];
#pragma unroll
  for (int dh = 0; dh < 2; ++dh) accO[dh] = (f32x4){0.f, 0.f, 0.f, 0.f};
  float m = -3.0e38f, l = 0.f;

  int kj = TID >> 2, kc = TID & 3;
  const _Float16* kbase = ka + ((size_t)bh * N + (size_t)js * 1024 + kj) * D + kc * 8;
  const _Float16* vbase = va + ((size_t)bh * N + (size_t)js * 1024 + kj) * D + kc * 8;
  int kdst = (kj * 64 + kc * 16) ^ ((kj & 3) << 4);

  h8 kreg = *(const h8*)kbase;
  h8 vreg = *(const h8*)vbase;

  for (int t = 0; t < ntiles; ++t) {
    __syncthreads();
    *(h8*)(Kc + kdst) = kreg;
#pragma unroll
    for (int e = 0; e < 8; ++e) {  // V transpose-scatter
      int d = kc * 8 + e;
      int addr = (d * 128 + kj * 2) ^ ((d & 7) << 4) ^ (((d >> 3) & 3) << 5);
      *(_Float16*)(Vc + addr) = vreg[e];
    }
    if (t + 1 < ntiles) {
      kreg = *(const h8*)(kbase + (size_t)(t + 1) * 64 * D);
      vreg = *(const h8*)(vbase + (size_t)(t + 1) * 64 * D);
    }
    __syncthreads();

    // ---- QK^T -> scores in log2 domain ----
    float pv[4][4];
    float tmax = -3.0e38f;
#pragma unroll
    for (int jt = 0; jt < 4; ++jt) {
      int krow = jt * 16 + il;
      h8 kf = *(const h8*)(Kc + ((krow * 64 + g * 16) ^ ((krow & 3) << 4)));
      f32x4 accS = (f32x4){0.f, 0.f, 0.f, 0.f};
      accS = __builtin_amdgcn_mfma_f32_16x16x32_f16(kf, qf, accS, 0, 0, 0);
#pragma unroll
      for (int e = 0; e < 4; ++e) {
        float xv = accS[e] * SCL2;
        pv[jt][e] = xv;
        tmax = fmaxf(tmax, xv);
      }
    }
    tmax = fmaxf(tmax, __shfl_xor(tmax, 16));
    tmax = fmaxf(tmax, __shfl_xor(tmax, 32));
    float mn = fmaxf(m, tmax);
    float corr = exp2f(m - mn);
    float ls = 0.f;
#pragma unroll
    for (int jt = 0; jt < 4; ++jt)
#pragma unroll
      for (int e = 0; e < 4; ++e) {
        float pe = exp2f(pv[jt][e] - mn);
        pv[jt][e] = pe;
        ls += pe;
      }
    ls += __shfl_xor(ls, 16);
    ls += __shfl_xor(ls, 32);
    l = l * corr + ls;
    m = mn;
#pragma unroll
    for (int dh = 0; dh < 2; ++dh)
#pragma unroll
      for (int e = 0; e < 4; ++e) accO[dh][e] *= corr;

    // ---- P -> wave-private LDS ----
#pragma unroll
    for (int jt = 0; jt < 4; ++jt) {
      h4 ph = {(_Float16)pv[jt][0], (_Float16)pv[jt][1],
               (_Float16)pv[jt][2], (_Float16)pv[jt][3]};
      *(h4*)(Pw + ((il * 128 + jt * 32 + g * 8) ^ ((il & 7) << 4))) = ph;
    }

    // ---- PV ----
#pragma unroll
    for (int jb = 0; jb < 2; ++jb) {
      h8 pf = *(const h8*)(Pw + ((il * 128 + jb * 64 + g * 16) ^ ((il & 7) << 4)));
#pragma unroll
      for (int dh = 0; dh < 2; ++dh) {
        int vrow = dh * 16 + il;
        int vaddr = (vrow * 128 + jb * 64 + g * 16) ^ ((vrow & 7) << 4) ^
                    (((vrow >> 3) & 3) << 5);
        h8 vf = *(const h8*)(Vc + vaddr);
        accO[dh] = __builtin_amdgcn_mfma_f32_16x16x32_f16(vf, pf, accO[dh], 0, 0, 0);
      }
    }
  }

  // epilogue: write op[js][b][h*32+d][n_q] (unnormalized) + m/l
  int b = bh >> 3, h = bh & 7;
#pragma unroll
  for (int dh = 0; dh < 2; ++dh)
#pragma unroll
    for (int e = 0; e < 4; ++e) {
      int d = dh * 16 + g * 4 + e;
      op[((size_t)((js * 2 + b) * C) + h * 32 + d) * N + n_q] = accO[dh][e];
    }
  if (g == 0) {
    size_t idx = (size_t)(js * BH + bh) * N + n_q;
    mp[idx] = m;
    lp[idx] = l;
  }
}

// ---------------- kernel 4: fused combine + output 1x1 conv ----------------
__global__ __launch_bounds__(256) void k_final(const float* __restrict__ op,
    const float* __restrict__ mp, const float* __restrict__ lp,
    const float* __restrict__ wo, const float* __restrict__ bo,
    float* __restrict__ out) {
  __shared__ float w_s[256 * 33];   // [c][o_local] transposed, padded
  __shared__ float a_s[256 * 33];   // [c][n_local] combined attention tile
  __shared__ float cwa[8 * 32], cwb[8 * 32];
  int nt = blockIdx.x & 63, oq = (blockIdx.x >> 6) & 7, b = blockIdx.x >> 9;
  int n0 = nt * 32, o0 = oq * 32;

  {
    int h = TID >> 5, n_l = TID & 31;
    size_t i0 = (size_t)(b * 8 + h) * N + n0 + n_l;
    size_t i1 = (size_t)(BH + b * 8 + h) * N + n0 + n_l;
    float m0 = mp[i0], m1 = mp[i1];
    float mg = fmaxf(m0, m1);
    float w0 = exp2f(m0 - mg), w1 = exp2f(m1 - mg);
    float inv = 1.f / (w0 * lp[i0] + w1 * lp[i1]);
    cwa[TID] = w0 * inv;
    cwb[TID] = w1 * inv;
  }
#pragma unroll
  for (int p = 0; p < 8; ++p) {
    int idx = p * 256 + TID;
    int o_l = idx >> 6, c4 = idx & 63;
    float4 wv = ((const float4*)wo)[(o0 + o_l) * 64 + c4];
    w_s[(c4 * 4 + 0) * 33 + o_l] = wv.x;
    w_s[(c4 * 4 + 1) * 33 + o_l] = wv.y;
    w_s[(c4 * 4 + 2) * 33 + o_l] = wv.z;
    w_s[(c4 * 4 + 3) * 33 + o_l] = wv.w;
  }
  __syncthreads();
#pragma unroll
  for (int p = 0; p < 8; ++p) {
    int idx = p * 256 + TID;
    int c = idx >> 3, n4 = idx & 7;
    int h = c >> 5;
    size_t base0 = ((size_t)(b * C + c)) * N + n0 + n4 * 4;
    size_t base1 = ((size_t)((2 + b) * C + c)) * N + n0 + n4 * 4;
    float4 v0 = *(const float4*)(op + base0);
    float4 v1 = *(const float4*)(op + base1);
    const float* ca = &cwa[h * 32 + n4 * 4];
    const float* cb = &cwb[h * 32 + n4 * 4];
    a_s[c * 33 + n4 * 4 + 0] = ca[0] * v0.x + cb[0] * v1.x;
    a_s[c * 33 + n4 * 4 + 1] = ca[1] * v0.y + cb[1] * v1.y;
    a_s[c * 33 + n4 * 4 + 2] = ca[2] * v0.z + cb[2] * v1.z;
    a_s[c * 33 + n4 * 4 + 3] = ca[3] * v0.w + cb[3] * v1.w;
  }
  __syncthreads();

  int n_l = TID & 31, og = TID >> 5;
  float acc[4] = {0.f, 0.f, 0.f, 0.f};
  for (int c = 0; c < 256; ++c) {
    float4 w4 = *(const float4*)&w_s[c * 33 + og * 4];
    float av = a_s[c * 33 + n_l];
    acc[0] += w4.x * av;
    acc[1] += w4.y * av;
    acc[2] += w4.z * av;
    acc[3] += w4.w * av;
  }
#pragma unroll
  for (int k = 0; k < 4; ++k) {
    int o = o0 + og * 4 + k;
    out[(size_t)(b * C + o) * N + n0 + n_l] = acc[k] + bo[o];
  }
}

extern "C" void kernel_launch(void* const* d_in, const int* in_sizes, int n_in,
                              void* d_out, int out_size, void* d_ws, size_t ws_size,
                              hipStream_t stream) {
  const float* x = (const float*)d_in[0];
  const float* gamma = (const float*)d_in[1];
  const float* beta = (const float*)d_in[2];
  const float* wk = (const float*)d_in[3];
  const float* wq = (const float*)d_in[4];
  const float* wv = (const float*)d_in[5];
  const float* wo = (const float*)d_in[6];
  const float* bo = (const float*)d_in[7];
  float* out = (float*)d_out;
  float* ws = (float*)d_ws;

  float* stats = ws;
  _Float16* qa = (_Float16*)(ws + 1024);
  _Float16* ka = qa + SZ;
  _Float16* va = ka + SZ;
  float* op = (float*)(va + SZ);          // [js][b][C][N] fp32, 2*SZ floats
  float* mp = op + 2 * SZ;                // [js*BH + bh][N]
  float* lp = mp + 2 * (size_t)BH * N;

  k_bnstats<<<256, 256, 0, stream>>>(x, gamma, beta, stats);
  k_proj<<<768, 256, 0, stream>>>(x, wk, wq, wv, stats, qa, ka, va);
  k_attn<<<1024, 256, 0, stream>>>(qa, ka, va, op, mp, lp);
  k_final<<<1024, 256, 0, stream>>>(op, mp, lp, wo, bo, out);
}

// Round 12
// 76.818 us; speedup vs baseline: 8.6071x; 1.1826x over previous
//
#include <hip/hip_runtime.h>

#define TID threadIdx.x

constexpr int B = 2, C = 256, N = 2048, H = 8, D = 32, BH = 16;
constexpr float EPS = 1e-5f;
constexpr float SCL2 = 0.25505654344454694f; // 32^-0.5 * log2(e)
constexpr size_t SZ = (size_t)BH * N * D;    // 1048576 elements per Q/K/V buffer

typedef _Float16 h8 __attribute__((ext_vector_type(8)));
typedef _Float16 h4 __attribute__((ext_vector_type(4)));
typedef float f32x4 __attribute__((ext_vector_type(4)));

// ---------------- kernel 1: batchnorm stats, BN-FOLDED: a = rstd*gamma, bb = beta - mean*a
__global__ __launch_bounds__(256) void k_bnstats(const float* __restrict__ x,
                                                 const float* __restrict__ gamma,
                                                 const float* __restrict__ beta,
                                                 float* __restrict__ stats) {
  int c = blockIdx.x;
  float s = 0.f, ss = 0.f;
  const float4* x4 = (const float4*)x;
  for (int k = 0; k < B; ++k) {
    const float4* p = x4 + (size_t)(k * C + c) * (N / 4);
    for (int i = TID; i < N / 4; i += 256) {
      float4 v = p[i];
      s += v.x + v.y + v.z + v.w;
      ss += v.x * v.x + v.y * v.y + v.z * v.z + v.w * v.w;
    }
  }
#pragma unroll
  for (int off = 32; off; off >>= 1) {
    s += __shfl_down(s, off);
    ss += __shfl_down(ss, off);
  }
  __shared__ float red[8];
  int w = TID >> 6;
  if ((TID & 63) == 0) { red[w] = s; red[4 + w] = ss; }
  __syncthreads();
  if (TID == 0) {
    float S = red[0] + red[1] + red[2] + red[3];
    float SS = red[4] + red[5] + red[6] + red[7];
    float mean = S * (1.f / (B * N));
    float var = SS * (1.f / (B * N)) - mean * mean;
    float a = rsqrtf(var + EPS) * gamma[c];
    stats[c] = a;
    stats[C + c] = beta[c] - mean * a;
  }
}

// ---------------- kernel 2: proj v3 — DS-instruction-minimized ----------------
// w transposed in LDS (w_t[c][ch]): thread's 8 h-weights = 2 contiguous b128 reads.
// x-read hoisted out of the h-loop (g = d>>2, h-invariant): 32 b64 reads total.
// Qa/Ka: fp16 [bh][n][d].  Va: fp16 TRANSPOSED [bh][d][n] (scatter global stores,
// L2-merged) so k_attn can stage V^T with a single b128 instead of 8 scalar writes.
__global__ __launch_bounds__(256) void k_proj(const float* __restrict__ x,
    const float* __restrict__ wk, const float* __restrict__ wq,
    const float* __restrict__ wv, const float* __restrict__ stats,
    _Float16* __restrict__ qa, _Float16* __restrict__ ka, _Float16* __restrict__ va) {
  int proj = blockIdx.x >> 8;
  int rem = blockIdx.x & 255;
  int b = rem >> 7;
  int n0 = (rem & 127) * 16;
  const float* w = proj == 0 ? wk : (proj == 1 ? wq : wv);
  _Float16* out = proj == 0 ? qa : (proj == 1 ? ka : va);

  __shared__ float w_t[32 * 264];  // [c][ch] transposed weights (+8 pad)
  __shared__ float xs[256 * 18];   // row (g+8c); col' = col ^ ((((row)>>4)&3)<<2)
  __shared__ float sab[512];       // a[c], bb[c]

  // stage BN consts + transposed weight tile: thread t owns w row ch=t (8 float4),
  // scatter-writes 32 b32 into column t (banks: (264c+t)%32 -> 2 lanes/bank, free)
  sab[TID] = stats[TID];
  sab[256 + TID] = stats[256 + TID];
  {
    const float4* wr4 = (const float4*)(w + TID * 32);
#pragma unroll
    for (int p = 0; p < 8; ++p) {
      float4 v = wr4[p];
      w_t[(p * 4 + 0) * 264 + TID] = v.x;
      w_t[(p * 4 + 1) * 264 + TID] = v.y;
      w_t[(p * 4 + 2) * 264 + TID] = v.z;
      w_t[(p * 4 + 3) * 264 + TID] = v.w;
    }
  }
  __syncthreads();  // sab ready for x staging
  // x tile with BN applied (float4 loads, float2 swizzled LDS writes)
#pragma unroll
  for (int p = 0; p < 4; ++p) {
    int c = p * 64 + (TID >> 2);
    int n4 = (TID & 3) * 4;
    float4 v = *(const float4*)(x + (size_t)(b * C + c) * N + n0 + n4);
    float a = sab[c], bb = sab[256 + c];
    int row = (c >> 5) + ((c & 31) << 3);  // g + 8c
    int swz = ((row >> 4) & 3) << 2;
    float2 lo = {v.x * a + bb, v.y * a + bb};
    float2 hi = {v.z * a + bb, v.w * a + bb};
    *(float2*)&xs[row * 18 + (n4 ^ swz)] = lo;
    *(float2*)&xs[row * 18 + ((n4 + 2) ^ swz)] = hi;
  }
  __syncthreads();

  // compute: thread (d, t2): 8 h-outputs for n = n0 + t2*2 + {0,1}
  int d = TID & 31, t2 = TID >> 5;
  int g = d >> 2;  // channel group, h-invariant
  float2 acc[8];
#pragma unroll
  for (int h = 0; h < 8; ++h) acc[h] = (float2){0.f, 0.f};
#pragma unroll
  for (int c = 0; c < 32; ++c) {
    float4 w0 = *(const float4*)&w_t[c * 264 + 8 * d];      // h = 0..3
    float4 w1 = *(const float4*)&w_t[c * 264 + 8 * d + 4];  // h = 4..7
    int row = g + 8 * c;
    int swz = ((row >> 4) & 3) << 2;
    float2 xv = *(const float2*)&xs[row * 18 + ((t2 * 2) ^ swz)];
    acc[0].x += w0.x * xv.x; acc[0].y += w0.x * xv.y;
    acc[1].x += w0.y * xv.x; acc[1].y += w0.y * xv.y;
    acc[2].x += w0.z * xv.x; acc[2].y += w0.z * xv.y;
    acc[3].x += w0.w * xv.x; acc[3].y += w0.w * xv.y;
    acc[4].x += w1.x * xv.x; acc[4].y += w1.x * xv.y;
    acc[5].x += w1.y * xv.x; acc[5].y += w1.y * xv.y;
    acc[6].x += w1.z * xv.x; acc[6].y += w1.z * xv.y;
    acc[7].x += w1.w * xv.x; acc[7].y += w1.w * xv.y;
  }
  int n = n0 + t2 * 2;
  if (proj < 2) {  // [bh][n][d]
#pragma unroll
    for (int h = 0; h < 8; ++h) {
      size_t o = ((size_t)((b * 8 + h) * N) + n) * D + d;
      out[o] = (_Float16)acc[h].x;
      out[o + D] = (_Float16)acc[h].y;
    }
  } else {         // V transposed: [bh][d][n]
#pragma unroll
    for (int h = 0; h < 8; ++h) {
      size_t o = ((size_t)((b * 8 + h) * D) + d) * N + n;
      out[o] = (_Float16)acc[h].x;
      out[o + 1] = (_Float16)acc[h].y;
    }
  }
}

// ---------------- kernel 3: MFMA fp16 flash attention (va pre-transposed) ----------------
__global__ __launch_bounds__(256, 4) void k_attn(
    const _Float16* __restrict__ qa, const _Float16* __restrict__ ka,
    const _Float16* __restrict__ va, float* __restrict__ op,
    float* __restrict__ mp, float* __restrict__ lp) {
  int bid = blockIdx.x;
  int r = bid & 7;          // XCD id (round-robin dispatch)
  int q = bid >> 3;         // 0..127
  int js = q >> 6;
  int bh = r * 2 + ((q >> 5) & 1);
  int rb = q & 31;
  constexpr int ntiles = 16;  // 1024 j's per js half

  int w = TID >> 6;
  int lane = TID & 63;
  int il = lane & 15;
  int g = lane >> 4;

  __shared__ char Kc[4096];      // K tile [64 j][32 d] fp16, rows 64B, swz ^((j&3)<<4)
  __shared__ char Vc[4096];      // V^T tile [32 d][64 j] fp16, rows 128B, swz f(d)
  __shared__ char Pc[4 * 2048];  // per-wave P^T [16 i][64 j] fp16, swz ^((i&7)<<4)
  char* Pw = Pc + w * 2048;

  int n_q = rb * 64 + w * 16 + il;
  h8 qf = *(const h8*)(qa + ((size_t)bh * N + n_q) * D + g * 8);

  f32x4 accO[2];
#pragma unroll
  for (int dh = 0; dh < 2; ++dh) accO[dh] = (f32x4){0.f, 0.f, 0.f, 0.f};
  float m = -3.0e38f, l = 0.f;

  // K staging: thread (kj, kc) covers K row kj, 16B chunk kc
  int kj = TID >> 2, kc = TID & 3;
  const _Float16* kbase = ka + ((size_t)bh * N + (size_t)js * 1024 + kj) * D + kc * 8;
  int kdst = (kj * 64 + kc * 16) ^ ((kj & 3) << 4);
  // V^T staging: thread (vd, vc) covers V^T row vd (d), 16B chunk vc (8 j's)
  int vd = TID >> 3, vc = TID & 7;
  const _Float16* vbase = va + ((size_t)bh * D + vd) * N + (size_t)js * 1024 + vc * 8;
  int vdst = (vd * 128 + vc * 16) ^ ((vd & 7) << 4) ^ (((vd >> 3) & 3) << 5);

  h8 kreg = *(const h8*)kbase;
  h8 vreg = *(const h8*)vbase;

  for (int t = 0; t < ntiles; ++t) {
    __syncthreads();
    *(h8*)(Kc + kdst) = kreg;
    *(h8*)(Vc + vdst) = vreg;
    if (t + 1 < ntiles) {
      kreg = *(const h8*)(kbase + (size_t)(t + 1) * 64 * D);
      vreg = *(const h8*)(vbase + (t + 1) * 64);
    }
    __syncthreads();

    // ---- QK^T -> scores in log2 domain ----
    float pv[4][4];
    float tmax = -3.0e38f;
#pragma unroll
    for (int jt = 0; jt < 4; ++jt) {
      int krow = jt * 16 + il;
      h8 kf = *(const h8*)(Kc + ((krow * 64 + g * 16) ^ ((krow & 3) << 4)));
      f32x4 accS = (f32x4){0.f, 0.f, 0.f, 0.f};
      accS = __builtin_amdgcn_mfma_f32_16x16x32_f16(kf, qf, accS, 0, 0, 0);
#pragma unroll
      for (int e = 0; e < 4; ++e) {
        float xv = accS[e] * SCL2;
        pv[jt][e] = xv;
        tmax = fmaxf(tmax, xv);
      }
    }
    tmax = fmaxf(tmax, __shfl_xor(tmax, 16));
    tmax = fmaxf(tmax, __shfl_xor(tmax, 32));
    float mn = fmaxf(m, tmax);
    float corr = exp2f(m - mn);
    float ls = 0.f;
#pragma unroll
    for (int jt = 0; jt < 4; ++jt)
#pragma unroll
      for (int e = 0; e < 4; ++e) {
        float pe = exp2f(pv[jt][e] - mn);
        pv[jt][e] = pe;
        ls += pe;
      }
    ls += __shfl_xor(ls, 16);
    ls += __shfl_xor(ls, 32);
    l = l * corr + ls;
    m = mn;
#pragma unroll
    for (int dh = 0; dh < 2; ++dh)
#pragma unroll
      for (int e = 0; e < 4; ++e) accO[dh][e] *= corr;

    // ---- P -> wave-private LDS ----
#pragma unroll
    for (int jt = 0; jt < 4; ++jt) {
      h4 ph = {(_Float16)pv[jt][0], (_Float16)pv[jt][1],
               (_Float16)pv[jt][2], (_Float16)pv[jt][3]};
      *(h4*)(Pw + ((il * 128 + jt * 32 + g * 8) ^ ((il & 7) << 4))) = ph;
    }

    // ---- PV ----
#pragma unroll
    for (int jb = 0; jb < 2; ++jb) {
      h8 pf = *(const h8*)(Pw + ((il * 128 + jb * 64 + g * 16) ^ ((il & 7) << 4)));
#pragma unroll
      for (int dh = 0; dh < 2; ++dh) {
        int vrow = dh * 16 + il;
        int vaddr = (vrow * 128 + jb * 64 + g * 16) ^ ((vrow & 7) << 4) ^
                    (((vrow >> 3) & 3) << 5);
        h8 vf = *(const h8*)(Vc + vaddr);
        accO[dh] = __builtin_amdgcn_mfma_f32_16x16x32_f16(vf, pf, accO[dh], 0, 0, 0);
      }
    }
  }

  // epilogue: write op[js][b][h*32+d][n_q] (unnormalized) + m/l
  int b = bh >> 3, h = bh & 7;
#pragma unroll
  for (int dh = 0; dh < 2; ++dh)
#pragma unroll
    for (int e = 0; e < 4; ++e) {
      int d = dh * 16 + g * 4 + e;
      op[((size_t)((js * 2 + b) * C) + h * 32 + d) * N + n_q] = accO[dh][e];
    }
  if (g == 0) {
    size_t idx = (size_t)(js * BH + bh) * N + n_q;
    mp[idx] = m;
    lp[idx] = l;
  }
}

// ---------------- kernel 4: fused combine + output 1x1 conv ----------------
__global__ __launch_bounds__(256) void k_final(const float* __restrict__ op,
    const float* __restrict__ mp, const float* __restrict__ lp,
    const float* __restrict__ wo, const float* __restrict__ bo,
    float* __restrict__ out) {
  __shared__ float w_s[256 * 33];   // [c][o_local] transposed, padded
  __shared__ float a_s[256 * 33];   // [c][n_local] combined attention tile
  __shared__ float cwa[8 * 32], cwb[8 * 32];
  int nt = blockIdx.x & 63, oq = (blockIdx.x >> 6) & 7, b = blockIdx.x >> 9;
  int n0 = nt * 32, o0 = oq * 32;

  {
    int h = TID >> 5, n_l = TID & 31;
    size_t i0 = (size_t)(b * 8 + h) * N + n0 + n_l;
    size_t i1 = (size_t)(BH + b * 8 + h) * N + n0 + n_l;
    float m0 = mp[i0], m1 = mp[i1];
    float mg = fmaxf(m0, m1);
    float w0 = exp2f(m0 - mg), w1 = exp2f(m1 - mg);
    float inv = 1.f / (w0 * lp[i0] + w1 * lp[i1]);
    cwa[TID] = w0 * inv;
    cwb[TID] = w1 * inv;
  }
#pragma unroll
  for (int p = 0; p < 8; ++p) {
    int idx = p * 256 + TID;
    int o_l = idx >> 6, c4 = idx & 63;
    float4 wv = ((const float4*)wo)[(o0 + o_l) * 64 + c4];
    w_s[(c4 * 4 + 0) * 33 + o_l] = wv.x;
    w_s[(c4 * 4 + 1) * 33 + o_l] = wv.y;
    w_s[(c4 * 4 + 2) * 33 + o_l] = wv.z;
    w_s[(c4 * 4 + 3) * 33 + o_l] = wv.w;
  }
  __syncthreads();
#pragma unroll
  for (int p = 0; p < 8; ++p) {
    int idx = p * 256 + TID;
    int c = idx >> 3, n4 = idx & 7;
    int h = c >> 5;
    size_t base0 = ((size_t)(b * C + c)) * N + n0 + n4 * 4;
    size_t base1 = ((size_t)((2 + b) * C + c)) * N + n0 + n4 * 4;
    float4 v0 = *(const float4*)(op + base0);
    float4 v1 = *(const float4*)(op + base1);
    const float* ca = &cwa[h * 32 + n4 * 4];
    const float* cb = &cwb[h * 32 + n4 * 4];
    a_s[c * 33 + n4 * 4 + 0] = ca[0] * v0.x + cb[0] * v1.x;
    a_s[c * 33 + n4 * 4 + 1] = ca[1] * v0.y + cb[1] * v1.y;
    a_s[c * 33 + n4 * 4 + 2] = ca[2] * v0.z + cb[2] * v1.z;
    a_s[c * 33 + n4 * 4 + 3] = ca[3] * v0.w + cb[3] * v1.w;
  }
  __syncthreads();

  int n_l = TID & 31, og = TID >> 5;
  float acc[4] = {0.f, 0.f, 0.f, 0.f};
  for (int c = 0; c < 256; ++c) {
    float4 w4 = *(const float4*)&w_s[c * 33 + og * 4];
    float av = a_s[c * 33 + n_l];
    acc[0] += w4.x * av;
    acc[1] += w4.y * av;
    acc[2] += w4.z * av;
    acc[3] += w4.w * av;
  }
#pragma unroll
  for (int k = 0; k < 4; ++k) {
    int o = o0 + og * 4 + k;
    out[(size_t)(b * C + o) * N + n0 + n_l] = acc[k] + bo[o];
  }
}

extern "C" void kernel_launch(void* const* d_in, const int* in_sizes, int n_in,
                              void* d_out, int out_size, void* d_ws, size_t ws_size,
                              hipStream_t stream) {
  const float* x = (const float*)d_in[0];
  const float* gamma = (const float*)d_in[1];
  const float* beta = (const float*)d_in[2];
  const float* wk = (const float*)d_in[3];
  const float* wq = (const float*)d_in[4];
  const float* wv = (const float*)d_in[5];
  const float* wo = (const float*)d_in[6];
  const float* bo = (const float*)d_in[7];
  float* out = (float*)d_out;
  float* ws = (float*)d_ws;

  float* stats = ws;
  _Float16* qa = (_Float16*)(ws + 1024);
  _Float16* ka = qa + SZ;
  _Float16* va = ka + SZ;               // [bh][d][n] transposed
  float* op = (float*)(va + SZ);        // [js][b][C][N] fp32, 2*SZ floats
  float* mp = op + 2 * SZ;              // [js*BH + bh][N]
  float* lp = mp + 2 * (size_t)BH * N;

  k_bnstats<<<256, 256, 0, stream>>>(x, gamma, beta, stats);
  k_proj<<<768, 256, 0, stream>>>(x, wk, wq, wv, stats, qa, ka, va);
  k_attn<<<1024, 256, 0, stream>>>(qa, ka, va, op, mp, lp);
  k_final<<<1024, 256, 0, stream>>>(op, mp, lp, wo, bo, out);
}

// Round 13
// 61.851 us; speedup vs baseline: 10.6898x; 1.2420x over previous
//
#include <hip/hip_runtime.h>

#define TID threadIdx.x

constexpr int B = 2, C = 256, N = 2048, H = 8, D = 32, BH = 16;
constexpr float EPS = 1e-5f;
constexpr float SCL2 = 0.25505654344454694f; // 32^-0.5 * log2(e)
constexpr size_t SZ = (size_t)BH * N * D;    // 1048576 elements per Q/K/V buffer

typedef _Float16 h8 __attribute__((ext_vector_type(8)));
typedef _Float16 h4 __attribute__((ext_vector_type(4)));
typedef float f32x4 __attribute__((ext_vector_type(4)));

// ---------------- kernel 1: batchnorm stats, BN-FOLDED: a = rstd*gamma, bb = beta - mean*a
__global__ __launch_bounds__(256) void k_bnstats(const float* __restrict__ x,
                                                 const float* __restrict__ gamma,
                                                 const float* __restrict__ beta,
                                                 float* __restrict__ stats) {
  int c = blockIdx.x;
  float s = 0.f, ss = 0.f;
  const float4* x4 = (const float4*)x;
  for (int k = 0; k < B; ++k) {
    const float4* p = x4 + (size_t)(k * C + c) * (N / 4);
    for (int i = TID; i < N / 4; i += 256) {
      float4 v = p[i];
      s += v.x + v.y + v.z + v.w;
      ss += v.x * v.x + v.y * v.y + v.z * v.z + v.w * v.w;
    }
  }
#pragma unroll
  for (int off = 32; off; off >>= 1) {
    s += __shfl_down(s, off);
    ss += __shfl_down(ss, off);
  }
  __shared__ float red[8];
  int w = TID >> 6;
  if ((TID & 63) == 0) { red[w] = s; red[4 + w] = ss; }
  __syncthreads();
  if (TID == 0) {
    float S = red[0] + red[1] + red[2] + red[3];
    float SS = red[4] + red[5] + red[6] + red[7];
    float mean = S * (1.f / (B * N));
    float var = SS * (1.f / (B * N)) - mean * mean;
    float a = rsqrtf(var + EPS) * gamma[c];
    stats[c] = a;
    stats[C + c] = beta[c] - mean * a;
  }
}

// ---------------- kernel 2: proj v3 — DS-instruction-minimized ----------------
__global__ __launch_bounds__(256) void k_proj(const float* __restrict__ x,
    const float* __restrict__ wk, const float* __restrict__ wq,
    const float* __restrict__ wv, const float* __restrict__ stats,
    _Float16* __restrict__ qa, _Float16* __restrict__ ka, _Float16* __restrict__ va) {
  int proj = blockIdx.x >> 8;
  int rem = blockIdx.x & 255;
  int b = rem >> 7;
  int n0 = (rem & 127) * 16;
  const float* w = proj == 0 ? wk : (proj == 1 ? wq : wv);
  _Float16* out = proj == 0 ? qa : (proj == 1 ? ka : va);

  __shared__ float w_t[32 * 264];  // [c][ch] transposed weights (+8 pad)
  __shared__ float xs[256 * 18];   // row (g+8c); col' = col ^ ((((row)>>4)&3)<<2)
  __shared__ float sab[512];       // a[c], bb[c]

  sab[TID] = stats[TID];
  sab[256 + TID] = stats[256 + TID];
  {
    const float4* wr4 = (const float4*)(w + TID * 32);
#pragma unroll
    for (int p = 0; p < 8; ++p) {
      float4 v = wr4[p];
      w_t[(p * 4 + 0) * 264 + TID] = v.x;
      w_t[(p * 4 + 1) * 264 + TID] = v.y;
      w_t[(p * 4 + 2) * 264 + TID] = v.z;
      w_t[(p * 4 + 3) * 264 + TID] = v.w;
    }
  }
  __syncthreads();
#pragma unroll
  for (int p = 0; p < 4; ++p) {
    int c = p * 64 + (TID >> 2);
    int n4 = (TID & 3) * 4;
    float4 v = *(const float4*)(x + (size_t)(b * C + c) * N + n0 + n4);
    float a = sab[c], bb = sab[256 + c];
    int row = (c >> 5) + ((c & 31) << 3);  // g + 8c
    int swz = ((row >> 4) & 3) << 2;
    float2 lo = {v.x * a + bb, v.y * a + bb};
    float2 hi = {v.z * a + bb, v.w * a + bb};
    *(float2*)&xs[row * 18 + (n4 ^ swz)] = lo;
    *(float2*)&xs[row * 18 + ((n4 + 2) ^ swz)] = hi;
  }
  __syncthreads();

  int d = TID & 31, t2 = TID >> 5;
  int g = d >> 2;  // channel group, h-invariant
  float2 acc[8];
#pragma unroll
  for (int h = 0; h < 8; ++h) acc[h] = (float2){0.f, 0.f};
#pragma unroll
  for (int c = 0; c < 32; ++c) {
    float4 w0 = *(const float4*)&w_t[c * 264 + 8 * d];      // h = 0..3
    float4 w1 = *(const float4*)&w_t[c * 264 + 8 * d + 4];  // h = 4..7
    int row = g + 8 * c;
    int swz = ((row >> 4) & 3) << 2;
    float2 xv = *(const float2*)&xs[row * 18 + ((t2 * 2) ^ swz)];
    acc[0].x += w0.x * xv.x; acc[0].y += w0.x * xv.y;
    acc[1].x += w0.y * xv.x; acc[1].y += w0.y * xv.y;
    acc[2].x += w0.z * xv.x; acc[2].y += w0.z * xv.y;
    acc[3].x += w0.w * xv.x; acc[3].y += w0.w * xv.y;
    acc[4].x += w1.x * xv.x; acc[4].y += w1.x * xv.y;
    acc[5].x += w1.y * xv.x; acc[5].y += w1.y * xv.y;
    acc[6].x += w1.z * xv.x; acc[6].y += w1.z * xv.y;
    acc[7].x += w1.w * xv.x; acc[7].y += w1.w * xv.y;
  }
  int n = n0 + t2 * 2;
  if (proj < 2) {  // [bh][n][d]
#pragma unroll
    for (int h = 0; h < 8; ++h) {
      size_t o = ((size_t)((b * 8 + h) * N) + n) * D + d;
      out[o] = (_Float16)acc[h].x;
      out[o + D] = (_Float16)acc[h].y;
    }
  } else {         // V transposed: [bh][d][n]
#pragma unroll
    for (int h = 0; h < 8; ++h) {
      size_t o = ((size_t)((b * 8 + h) * D) + d) * N + n;
      out[o] = (_Float16)acc[h].x;
      out[o + 1] = (_Float16)acc[h].y;
    }
  }
}

// ---------------- kernel 3: MFMA fp16 flash attention ----------------
// Epilogue writes op in [js*2+b][n][ch] layout (b128 stores) for MFMA k_final.
__global__ __launch_bounds__(256, 4) void k_attn(
    const _Float16* __restrict__ qa, const _Float16* __restrict__ ka,
    const _Float16* __restrict__ va, float* __restrict__ op,
    float* __restrict__ mp, float* __restrict__ lp) {
  int bid = blockIdx.x;
  int r = bid & 7;          // XCD id (round-robin dispatch)
  int q = bid >> 3;         // 0..127
  int js = q >> 6;
  int bh = r * 2 + ((q >> 5) & 1);
  int rb = q & 31;
  constexpr int ntiles = 16;  // 1024 j's per js half

  int w = TID >> 6;
  int lane = TID & 63;
  int il = lane & 15;
  int g = lane >> 4;

  __shared__ char Kc[4096];      // K tile [64 j][32 d] fp16, rows 64B, swz ^((j&3)<<4)
  __shared__ char Vc[4096];      // V^T tile [32 d][64 j] fp16, rows 128B, swz f(d)
  __shared__ char Pc[4 * 2048];  // per-wave P^T [16 i][64 j] fp16, swz ^((i&7)<<4)
  char* Pw = Pc + w * 2048;

  int n_q = rb * 64 + w * 16 + il;
  h8 qf = *(const h8*)(qa + ((size_t)bh * N + n_q) * D + g * 8);

  f32x4 accO[2];
#pragma unroll
  for (int dh = 0; dh < 2; ++dh) accO[dh] = (f32x4){0.f, 0.f, 0.f, 0.f};
  float m = -3.0e38f, l = 0.f;

  int kj = TID >> 2, kc = TID & 3;
  const _Float16* kbase = ka + ((size_t)bh * N + (size_t)js * 1024 + kj) * D + kc * 8;
  int kdst = (kj * 64 + kc * 16) ^ ((kj & 3) << 4);
  int vd = TID >> 3, vc = TID & 7;
  const _Float16* vbase = va + ((size_t)bh * D + vd) * N + (size_t)js * 1024 + vc * 8;
  int vdst = (vd * 128 + vc * 16) ^ ((vd & 7) << 4) ^ (((vd >> 3) & 3) << 5);

  h8 kreg = *(const h8*)kbase;
  h8 vreg = *(const h8*)vbase;

  for (int t = 0; t < ntiles; ++t) {
    __syncthreads();
    *(h8*)(Kc + kdst) = kreg;
    *(h8*)(Vc + vdst) = vreg;
    if (t + 1 < ntiles) {
      kreg = *(const h8*)(kbase + (size_t)(t + 1) * 64 * D);
      vreg = *(const h8*)(vbase + (t + 1) * 64);
    }
    __syncthreads();

    // ---- QK^T -> scores in log2 domain ----
    float pv[4][4];
    float tmax = -3.0e38f;
#pragma unroll
    for (int jt = 0; jt < 4; ++jt) {
      int krow = jt * 16 + il;
      h8 kf = *(const h8*)(Kc + ((krow * 64 + g * 16) ^ ((krow & 3) << 4)));
      f32x4 accS = (f32x4){0.f, 0.f, 0.f, 0.f};
      accS = __builtin_amdgcn_mfma_f32_16x16x32_f16(kf, qf, accS, 0, 0, 0);
#pragma unroll
      for (int e = 0; e < 4; ++e) {
        float xv = accS[e] * SCL2;
        pv[jt][e] = xv;
        tmax = fmaxf(tmax, xv);
      }
    }
    tmax = fmaxf(tmax, __shfl_xor(tmax, 16));
    tmax = fmaxf(tmax, __shfl_xor(tmax, 32));
    float mn = fmaxf(m, tmax);
    float corr = exp2f(m - mn);
    float ls = 0.f;
#pragma unroll
    for (int jt = 0; jt < 4; ++jt)
#pragma unroll
      for (int e = 0; e < 4; ++e) {
        float pe = exp2f(pv[jt][e] - mn);
        pv[jt][e] = pe;
        ls += pe;
      }
    ls += __shfl_xor(ls, 16);
    ls += __shfl_xor(ls, 32);
    l = l * corr + ls;
    m = mn;
#pragma unroll
    for (int dh = 0; dh < 2; ++dh)
#pragma unroll
      for (int e = 0; e < 4; ++e) accO[dh][e] *= corr;

    // ---- P -> wave-private LDS ----
#pragma unroll
    for (int jt = 0; jt < 4; ++jt) {
      h4 ph = {(_Float16)pv[jt][0], (_Float16)pv[jt][1],
               (_Float16)pv[jt][2], (_Float16)pv[jt][3]};
      *(h4*)(Pw + ((il * 128 + jt * 32 + g * 8) ^ ((il & 7) << 4))) = ph;
    }

    // ---- PV ----
#pragma unroll
    for (int jb = 0; jb < 2; ++jb) {
      h8 pf = *(const h8*)(Pw + ((il * 128 + jb * 64 + g * 16) ^ ((il & 7) << 4)));
#pragma unroll
      for (int dh = 0; dh < 2; ++dh) {
        int vrow = dh * 16 + il;
        int vaddr = (vrow * 128 + jb * 64 + g * 16) ^ ((vrow & 7) << 4) ^
                    (((vrow >> 3) & 3) << 5);
        h8 vf = *(const h8*)(Vc + vaddr);
        accO[dh] = __builtin_amdgcn_mfma_f32_16x16x32_f16(vf, pf, accO[dh], 0, 0, 0);
      }
    }
  }

  // epilogue: op[(js*2+b)][n_q][ch], ch = h*32 + dh*16 + g*4 + e  (2x b128)
  int b = bh >> 3, h = bh & 7;
  size_t obase = ((size_t)((js * 2 + b) * N) + n_q) * C + h * 32;
#pragma unroll
  for (int dh = 0; dh < 2; ++dh) {
    float4 o4 = {accO[dh][0], accO[dh][1], accO[dh][2], accO[dh][3]};
    *(float4*)(op + obase + dh * 16 + g * 4) = o4;
  }
  if (g == 0) {
    size_t idx = (size_t)(js * BH + bh) * N + n_q;
    mp[idx] = m;
    lp[idx] = l;
  }
}

// ---------------- kernel 4: MFMA combine + output 1x1 conv ----------------
// out[b,o,n] = sum_c wo[o,c]*(cw0[h,n]*op0[b,n,c] + cw1[h,n]*op1[b,n,c]) + bo[o]
// 32o x 32n tile; wo split hi+lo fp16 (exact); a-tile fp16. 8 K-steps of 32.
__global__ __launch_bounds__(256) void k_final(const float* __restrict__ op,
    const float* __restrict__ mp, const float* __restrict__ lp,
    const float* __restrict__ wo, const float* __restrict__ bo,
    float* __restrict__ out) {
  __shared__ _Float16 woh[32 * 256];  // [o][c] swz ^((o&7)<<4) on byte addr
  __shared__ _Float16 wol[32 * 256];
  __shared__ _Float16 as_[32 * 256];  // [n][c] swz ^((n&7)<<4)
  __shared__ float cwa[8 * 32], cwb[8 * 32];
  __shared__ float bos[32];
  int nt = blockIdx.x & 63, oq = (blockIdx.x >> 6) & 7, b = blockIdx.x >> 9;
  int n0 = nt * 32, o0 = oq * 32;

  // combine weights per (h, n_local)
  {
    int h = TID >> 5, n_l = TID & 31;
    size_t i0 = (size_t)(b * 8 + h) * N + n0 + n_l;
    size_t i1 = (size_t)(BH + b * 8 + h) * N + n0 + n_l;
    float m0 = mp[i0], m1 = mp[i1];
    float mg = fmaxf(m0, m1);
    float w0 = exp2f(m0 - mg), w1 = exp2f(m1 - mg);
    float inv = 1.f / (w0 * lp[i0] + w1 * lp[i1]);
    cwa[TID] = w0 * inv;
    cwb[TID] = w1 * inv;
  }
  if (TID < 32) bos[TID] = bo[o0 + TID];
  // wo tile: hi/lo fp16 split. thread: c-chunk = TID&63 (c = 4*that), o = (TID>>6) + p*4
  {
    int cc = TID & 63;
    int ob = TID >> 6;
#pragma unroll
    for (int p = 0; p < 8; ++p) {
      int o = ob + p * 4;
      float4 v = ((const float4*)wo)[(o0 + o) * 64 + cc];
      _Float16 h0 = (_Float16)v.x, h1 = (_Float16)v.y,
               h2 = (_Float16)v.z, h3 = (_Float16)v.w;
      h4 hi = {h0, h1, h2, h3};
      h4 lo = {(_Float16)(v.x - (float)h0), (_Float16)(v.y - (float)h1),
               (_Float16)(v.z - (float)h2), (_Float16)(v.w - (float)h3)};
      int byte = (o * 512 + cc * 8) ^ ((o & 7) << 4);
      *(h4*)((char*)woh + byte) = hi;
      *(h4*)((char*)wol + byte) = lo;
    }
  }
  __syncthreads();  // cwa/cwb ready before a_s staging uses them
  // a tile: combined fp16 [n][c]. thread: c-chunk = TID&63, n = (TID>>6) + p*4
  {
    int cc = TID & 63;
    int h = cc >> 3;  // c = cc*4 -> h = c>>5 = cc>>3
    int nb = TID >> 6;
#pragma unroll
    for (int p = 0; p < 8; ++p) {
      int n = nb + p * 4;
      float4 v0 = *(const float4*)(op + ((size_t)(b * N) + n0 + n) * C + cc * 4);
      float4 v1 = *(const float4*)(op + ((size_t)((2 + b) * N) + n0 + n) * C + cc * 4);
      float ca = cwa[h * 32 + n], cb = cwb[h * 32 + n];
      h4 av = {(_Float16)(ca * v0.x + cb * v1.x), (_Float16)(ca * v0.y + cb * v1.y),
               (_Float16)(ca * v0.z + cb * v1.z), (_Float16)(ca * v0.w + cb * v1.w)};
      int byte = (n * 512 + cc * 8) ^ ((n & 7) << 4);
      *(h4*)((char*)as_ + byte) = av;
    }
  }
  __syncthreads();

  // compute: wave w: o half (w&1)*16, n half (w>>1)*16; lane (il, g)
  int w = TID >> 6, lane = TID & 63, il = lane & 15, g = lane >> 4;
  int ow = (w & 1) * 16, nw = (w >> 1) * 16;
  f32x4 acc = (f32x4){0.f, 0.f, 0.f, 0.f};
#pragma unroll
  for (int ks = 0; ks < 8; ++ks) {
    int abyte = ((nw + il) * 512 + ks * 64 + g * 16) ^ ((il & 7) << 4);
    h8 bf = *(const h8*)((char*)as_ + abyte);
    int wbyte = ((ow + il) * 512 + ks * 64 + g * 16) ^ ((il & 7) << 4);
    h8 ah = *(const h8*)((char*)woh + wbyte);
    h8 al = *(const h8*)((char*)wol + wbyte);
    acc = __builtin_amdgcn_mfma_f32_16x16x32_f16(ah, bf, acc, 0, 0, 0);
    acc = __builtin_amdgcn_mfma_f32_16x16x32_f16(al, bf, acc, 0, 0, 0);
  }
  // D: col = il -> n, row = g*4+r -> o
  int n = n0 + nw + il;
#pragma unroll
  for (int r = 0; r < 4; ++r) {
    int o_l = ow + g * 4 + r;
    out[(size_t)(b * C + o0 + o_l) * N + n] = acc[r] + bos[o_l];
  }
}

extern "C" void kernel_launch(void* const* d_in, const int* in_sizes, int n_in,
                              void* d_out, int out_size, void* d_ws, size_t ws_size,
                              hipStream_t stream) {
  const float* x = (const float*)d_in[0];
  const float* gamma = (const float*)d_in[1];
  const float* beta = (const float*)d_in[2];
  const float* wk = (const float*)d_in[3];
  const float* wq = (const float*)d_in[4];
  const float* wv = (const float*)d_in[5];
  const float* wo = (const float*)d_in[6];
  const float* bo = (const float*)d_in[7];
  float* out = (float*)d_out;
  float* ws = (float*)d_ws;

  float* stats = ws;
  _Float16* qa = (_Float16*)(ws + 1024);
  _Float16* ka = qa + SZ;
  _Float16* va = ka + SZ;               // [bh][d][n] transposed
  float* op = (float*)(va + SZ);        // [js*2+b][n][ch] fp32, 2*SZ floats
  float* mp = op + 2 * SZ;              // [js*BH + bh][N]
  float* lp = mp + 2 * (size_t)BH * N;

  k_bnstats<<<256, 256, 0, stream>>>(x, gamma, beta, stats);
  k_proj<<<768, 256, 0, stream>>>(x, wk, wq, wv, stats, qa, ka, va);
  k_attn<<<1024, 256, 0, stream>>>(qa, ka, va, op, mp, lp);
  k_final<<<1024, 256, 0, stream>>>(op, mp, lp, wo, bo, out);
}